// Round 5
// baseline (104.794 us; speedup 1.0000x reference)
//
#include <hip/hip_runtime.h>
#include <hip/hip_bf16.h>
#include <math.h>

// B=1024, N=500, D=128, H=8, L=2, CLIP=10
constexpr int NKEY = 500;
constexpr int DIM = 128;
constexpr int ROWSTRIDE = 256;   // D*L floats per K/V row

typedef __attribute__((ext_vector_type(4))) float f32x4;

__device__ __forceinline__ f32x4 nt_load4(const float* p) {
    return __builtin_nontemporal_load((const f32x4*)p);
}
__device__ __forceinline__ void nt_store(float* p, float v) {
    __builtin_nontemporal_store(v, p);
}

__global__ __launch_bounds__(256, 4)
void fused_pomo_attn(const float* __restrict__ query,   // (B,1,128)
                     const float* __restrict__ K_att,   // (B,500,256)
                     const float* __restrict__ V_att,   // (B,500,256)
                     const int*   __restrict__ mask,    // (B,500) int32 0/1
                     const float* __restrict__ W0_w,    // (128,128)
                     const float* __restrict__ W0_b,    // (128,)
                     const float* __restrict__ Wq_w,    // (128,128)
                     const float* __restrict__ Wq_b,    // (128,)
                     float* __restrict__ out)           // (B,500)
{
    const int b = blockIdx.x;
    const int tid = threadIdx.x;
    const int lane32 = tid & 31;   // position within a 32-lane row group
    const int grp = tid >> 5;      // row group 0..7

    __shared__ alignas(16) float s_red[8][DIM];      // per-group PV partial acc
    __shared__ float s_m8[8][32];                    // per-group running max (per lane)
    __shared__ float s_l8[8][32];                    // per-group running sum
    __shared__ alignas(16) float s_out[DIM];         // layer-0 attention output
    __shared__ alignas(16) float s_q1[DIM];          // after W0
    __shared__ alignas(16) float s_qf[DIM];          // after Wq
    __shared__ alignas(16) float s_s1[NKEY];         // layer-1 scores (compacted)
    __shared__ int s_idx[NKEY];                      // compacted unmasked indices
    __shared__ int s_cnt;
    __shared__ float s_m[4], s_l[4];

    const size_t brow = (size_t)b * NKEY;

    // ---------- Pass 0: ordered compaction of unmasked indices (wave 0) ----------
    if (tid < 64) {
        int off = 0;
        for (int base = 0; base < NKEY; base += 64) {
            const int n = base + tid;
            const bool keep = (n < NKEY) && (mask[brow + n] == 0);
            const unsigned long long bal = __ballot(keep);
            const int pre = __popcll(bal & ((1ull << tid) - 1ull));
            if (keep) s_idx[off + pre] = n;
            off += __popcll(bal);
        }
        if (tid == 0) s_cnt = off;
    }
    __syncthreads();
    const int M = s_cnt;   // >= 1 (position 0 never masked)
    const int Mm1 = M - 1;

    // ---------- Pass 1 (flash-merged, 8x unrolled): layer-0 scores + online softmax + PV ----------
    // 32 lanes per row, lane c holds dims [4c,4c+4); head = c>>2 (dh=16)
    {
        const f32x4 q4 = ((const f32x4*)(query + (size_t)b * DIM))[lane32];
        const float* Kb = K_att + brow * ROWSTRIDE + lane32 * 4;
        const float* Vb = V_att + brow * ROWSTRIDE + lane32 * 4;
        float m = -1e30f, l = 0.f;
        f32x4 acc; acc[0]=0.f; acc[1]=0.f; acc[2]=0.f; acc[3]=0.f;
        for (int base = 0; base < M; base += 64) {
            int n[8]; bool okv[8];
            #pragma unroll
            for (int j = 0; j < 8; j++) {
                const int p = base + 8*j + grp;
                okv[j] = p < M;
                n[j] = s_idx[okv[j] ? p : Mm1];
            }
            f32x4 k[8], v[8];
            #pragma unroll
            for (int j = 0; j < 8; j++) k[j] = nt_load4(Kb + (size_t)n[j] * ROWSTRIDE);
            #pragma unroll
            for (int j = 0; j < 8; j++) v[j] = nt_load4(Vb + (size_t)n[j] * ROWSTRIDE);
            float s[8];
            #pragma unroll
            for (int j = 0; j < 8; j++)
                s[j] = q4[0]*k[j][0] + q4[1]*k[j][1] + q4[2]*k[j][2] + q4[3]*k[j][3];
            #pragma unroll
            for (int j = 0; j < 8; j++) { s[j] += __shfl_xor(s[j], 1); s[j] += __shfl_xor(s[j], 2); }
            #pragma unroll
            for (int j = 0; j < 8; j++) s[j] = okv[j] ? s[j] * 0.25f : -1e30f;  // 1/sqrt(16)
            float m2 = m;
            #pragma unroll
            for (int j = 0; j < 8; j++) m2 = fmaxf(m2, s[j]);
            const float f = __expf(m - m2);
            float w[8];
            #pragma unroll
            for (int j = 0; j < 8; j++) w[j] = __expf(s[j] - m2);   // invalid -> exp(-huge)=0
            l = l * f + ((w[0]+w[1]) + (w[2]+w[3])) + ((w[4]+w[5]) + (w[6]+w[7]));
            #pragma unroll
            for (int d = 0; d < 4; d++) {
                float a = acc[d] * f;
                #pragma unroll
                for (int j = 0; j < 8; j++) a += w[j] * v[j][d];
                acc[d] = a;
            }
            m = m2;
        }
        ((f32x4*)s_red[grp])[lane32] = acc;
        s_m8[grp][lane32] = m;
        s_l8[grp][lane32] = l;
    }
    __syncthreads();
    // merge the 8 per-group online-softmax partials (dim d held by quad-lane d>>2)
    if (tid < DIM) {
        const int ql = tid >> 2;
        float M_ = -1e30f;
        #pragma unroll
        for (int g = 0; g < 8; g++) M_ = fmaxf(M_, s_m8[g][ql]);
        float L = 0.f, o = 0.f;
        #pragma unroll
        for (int g = 0; g < 8; g++) {
            const float f = __expf(s_m8[g][ql] - M_);
            L += s_l8[g][ql] * f;
            o += s_red[g][tid] * f;
        }
        s_out[tid] = o / L;
    }
    __syncthreads();

    // ---------- Pass 4: q1 = s_out @ W0^T + b (2 threads per output) ----------
    {
        const int i = tid >> 1, half = tid & 1;
        const float4* wrow = (const float4*)(W0_w + (size_t)i * DIM + half * 64);
        float ssum = 0.f;
        #pragma unroll
        for (int k = 0; k < 16; k++) {
            const float4 w4 = wrow[k];
            const float4 o4 = ((const float4*)s_out)[half * 16 + k];
            ssum += w4.x*o4.x + w4.y*o4.y + w4.z*o4.z + w4.w*o4.w;
        }
        ssum += __shfl_xor(ssum, 1);
        if (half == 0) s_q1[i] = ssum + W0_b[i];
    }
    __syncthreads();

    // ---------- Pass 5: qf = s_q1 @ Wq^T + b ----------
    {
        const int i = tid >> 1, half = tid & 1;
        const float4* wrow = (const float4*)(Wq_w + (size_t)i * DIM + half * 64);
        float ssum = 0.f;
        #pragma unroll
        for (int k = 0; k < 16; k++) {
            const float4 w4 = wrow[k];
            const float4 o4 = ((const float4*)s_q1)[half * 16 + k];
            ssum += w4.x*o4.x + w4.y*o4.y + w4.z*o4.z + w4.w*o4.w;
        }
        ssum += __shfl_xor(ssum, 1);
        if (half == 0) s_qf[i] = ssum + Wq_b[i];
    }
    __syncthreads();

    // ---------- Pass 6: layer-1 scores over compacted rows (16x unrolled) ----------
    {
        const f32x4 qf4 = ((const f32x4*)s_qf)[lane32];
        const float* K1b = K_att + brow * ROWSTRIDE + DIM + lane32 * 4;
        for (int base = 0; base < M; base += 128) {
            int p[16]; bool ok[16]; int n[16];
            #pragma unroll
            for (int j = 0; j < 16; j++) {
                p[j] = base + 8*j + grp;
                ok[j] = p[j] < M;
                n[j] = s_idx[ok[j] ? p[j] : Mm1];
            }
            f32x4 k[16];
            #pragma unroll
            for (int j = 0; j < 16; j++) k[j] = nt_load4(K1b + (size_t)n[j] * ROWSTRIDE);
            float s[16];
            #pragma unroll
            for (int j = 0; j < 16; j++)
                s[j] = qf4[0]*k[j][0] + qf4[1]*k[j][1] + qf4[2]*k[j][2] + qf4[3]*k[j][3];
            #pragma unroll
            for (int o = 1; o < 32; o <<= 1) {
                #pragma unroll
                for (int j = 0; j < 16; j++) s[j] += __shfl_xor(s[j], o);
            }
            if (lane32 == 0) {
                #pragma unroll
                for (int j = 0; j < 16; j++)
                    if (ok[j]) s_s1[p[j]] = 10.f * tanhf(s[j] * 0.08838834764831845f);
            }
        }
    }
    // zero the full output row (masked positions are exactly 0)
    for (int n = tid; n < NKEY; n += 256) nt_store(out + brow + n, 0.f);
    __syncthreads();

    // ---------- Pass 7: block softmax over M + scatter write ----------
    {
        const int wid = tid >> 6;
        const int lane = tid & 63;
        float m = -INFINITY;
        for (int p = tid; p < M; p += 256) m = fmaxf(m, s_s1[p]);
        #pragma unroll
        for (int o = 32; o > 0; o >>= 1) m = fmaxf(m, __shfl_xor(m, o));
        if (lane == 0) s_m[wid] = m;
        __syncthreads();
        m = fmaxf(fmaxf(s_m[0], s_m[1]), fmaxf(s_m[2], s_m[3]));
        float l = 0.f;
        for (int p = tid; p < M; p += 256) {
            const float e = __expf(s_s1[p] - m);
            s_s1[p] = e;
            l += e;
        }
        #pragma unroll
        for (int o = 32; o > 0; o >>= 1) l += __shfl_xor(l, o);
        if (lane == 0) s_l[wid] = l;
        __syncthreads();
        l = s_l[0] + s_l[1] + s_l[2] + s_l[3];
        const float inv = 1.f / l;
        for (int p = tid; p < M; p += 256) nt_store(out + brow + s_idx[p], s_s1[p] * inv);
    }
}

extern "C" void kernel_launch(void* const* d_in, const int* in_sizes, int n_in,
                              void* d_out, int out_size, void* d_ws, size_t ws_size,
                              hipStream_t stream) {
    const float* query = (const float*)d_in[0];
    const float* K_att = (const float*)d_in[1];
    const float* V_att = (const float*)d_in[2];
    const int*   mask  = (const int*)d_in[3];
    const float* W0_w  = (const float*)d_in[4];
    const float* W0_b  = (const float*)d_in[5];
    const float* Wq_w  = (const float*)d_in[6];
    const float* Wq_b  = (const float*)d_in[7];
    float* out = (float*)d_out;

    const int B = in_sizes[0] / DIM;   // 1024
    fused_pomo_attn<<<B, 256, 0, stream>>>(query, K_att, V_att, mask,
                                           W0_w, W0_b, Wq_w, Wq_b, out);
}